// Round 5
// baseline (334.640 us; speedup 1.0000x reference)
//
#include <hip/hip_runtime.h>
#include <hip/hip_cooperative_groups.h>
#include <math.h>

#define B_ 32
#define C_ 256
#define HW_ 3136      // 56*56
#define HW4_ 784      // HW/4 (float4 = 16B chunks)
#define G_ 32
#define EPS_ 1e-5f

// ws layout (floats):
//   [0 .. 8191]   pooled[b*C + c]
//   [8192 ..]     gs[c], gsh[c], ms[c], msh[c]  (256 each)
#define WS_POOL 0
#define WS_GS   (B_ * C_)
#define WS_GSH  (B_ * C_ + C_)
#define WS_MS   (B_ * C_ + 2 * C_)
#define WS_MSH  (B_ * C_ + 3 * C_)

// 2048 blocks x 256 threads; 8 blocks/CU co-resident (VGPR capped at 64 via
// launch_bounds). Each block owns 4 consecutive planes (one per wave); all 4
// share the same batch index b since 4 | 256.
__global__ __launch_bounds__(256, 8) void fused_kernel(
    const float* __restrict__ x,
    const float* __restrict__ alpha_w, const float* __restrict__ alpha_b,
    const float* __restrict__ g_w, const float* __restrict__ g_b,
    const float* __restrict__ g_rm, const float* __restrict__ g_rv,
    const float* __restrict__ grp_w, const float* __restrict__ grp_b,
    const float* __restrict__ grp_rm, const float* __restrict__ grp_rv,
    float* __restrict__ ws,
    float* __restrict__ out) {
    const int blk  = blockIdx.x;          // 0..2047
    const int tid  = threadIdx.x;
    const int wv   = tid >> 6;
    const int lane = tid & 63;
    const int p0   = blk << 2;            // first plane of this block
    const int b    = p0 >> 8;             // batch index (same for all 4 planes)
    const int plane = p0 + wv;            // this wave's plane
    const int c     = plane & (C_ - 1);

    // batch-independent param fold: block k (k<256) handles channel k, wave 0
    if (blk < C_ && tid < G_) {
        const int ch = blk;
        const int g  = tid;
        float sg = grp_w[g * C_ + ch] * rsqrtf(grp_rv[g * C_ + ch] + EPS_);
        float sh = grp_b[g * C_ + ch] - grp_rm[g * C_ + ch] * sg;
        #pragma unroll
        for (int off = 16; off; off >>= 1) {
            sg += __shfl_down(sg, off);
            sh += __shfl_down(sh, off);
        }
        if (g == 0) {
            ws[WS_MS  + ch] = sg * (1.f / G_);
            ws[WS_MSH + ch] = sh * (1.f / G_);
            float gsv = g_w[ch] * rsqrtf(g_rv[ch] + EPS_);
            ws[WS_GS  + ch] = gsv;
            ws[WS_GSH + ch] = g_b[ch] - g_rm[ch] * gsv;
        }
    }

    // phase 1: wave-per-plane pooling (no LDS, no __syncthreads)
    {
        const float4* __restrict__ p = (const float4*)(x + (size_t)plane * HW_);
        float s = 0.f;
        for (int i = lane; i < HW4_; i += 64) {
            float4 v = p[i];
            s += v.x + v.y + v.z + v.w;
        }
        #pragma unroll
        for (int off = 32; off; off >>= 1) s += __shfl_down(s, off);
        if (lane == 0) ws[WS_POOL + plane] = s * (1.f / HW_);
    }

    cooperative_groups::this_grid().sync();

    // alpha[b] = sigmoid(dot(pooled[b,:], alpha_w) + alpha_b)  (block-wide)
    float s = ws[WS_POOL + b * C_ + tid] * alpha_w[tid];
    #pragma unroll
    for (int off = 32; off; off >>= 1) s += __shfl_down(s, off);
    __shared__ float red[4];
    __shared__ float a_sh;
    if (lane == 0) red[wv] = s;
    __syncthreads();
    if (tid == 0) {
        float z = red[0] + red[1] + red[2] + red[3] + alpha_b[0];
        a_sh = 1.f / (1.f + __expf(-z));
    }
    __syncthreads();
    const float a = a_sh;

    // phase 2: wave-per-plane apply (x is L3-hot from phase 1)
    const float gs  = ws[WS_GS  + c], gsh = ws[WS_GSH + c];
    const float ms  = ws[WS_MS  + c], msh = ws[WS_MSH + c];
    const float sc = fmaf(a, ms - gs, gs);      // (1-a)*gs + a*ms
    const float sh = fmaf(a, msh - gsh, gsh);

    const float4* __restrict__ px = (const float4*)(x + (size_t)plane * HW_);
    float4* __restrict__ po = (float4*)(out + (size_t)plane * HW_);
    for (int i = lane; i < HW4_; i += 64) {
        float4 v = px[i];
        float4 r;
        r.x = fmaf(v.x, sc, sh);
        r.y = fmaf(v.y, sc, sh);
        r.z = fmaf(v.z, sc, sh);
        r.w = fmaf(v.w, sc, sh);
        __builtin_nontemporal_store(r.x, &po[i].x);
        __builtin_nontemporal_store(r.y, &po[i].y);
        __builtin_nontemporal_store(r.z, &po[i].z);
        __builtin_nontemporal_store(r.w, &po[i].w);
    }
}

extern "C" void kernel_launch(void* const* d_in, const int* in_sizes, int n_in,
                              void* d_out, int out_size, void* d_ws, size_t ws_size,
                              hipStream_t stream) {
    const float* x       = (const float*)d_in[0];
    const float* alpha_w = (const float*)d_in[2];
    const float* alpha_b = (const float*)d_in[3];
    const float* g_w     = (const float*)d_in[4];
    const float* g_b     = (const float*)d_in[5];
    const float* g_rm    = (const float*)d_in[6];
    const float* g_rv    = (const float*)d_in[7];
    const float* grp_w   = (const float*)d_in[8];
    const float* grp_b   = (const float*)d_in[9];
    const float* grp_rm  = (const float*)d_in[10];
    const float* grp_rv  = (const float*)d_in[11];
    float* out = (float*)d_out;
    float* ws  = (float*)d_ws;

    void* args[] = {
        (void*)&x, (void*)&alpha_w, (void*)&alpha_b,
        (void*)&g_w, (void*)&g_b, (void*)&g_rm, (void*)&g_rv,
        (void*)&grp_w, (void*)&grp_b, (void*)&grp_rm, (void*)&grp_rv,
        (void*)&ws, (void*)&out
    };
    hipLaunchCooperativeKernel((void*)fused_kernel, dim3(B_ * C_ / 4), dim3(256),
                               args, 0, stream);
}